// Round 4
// baseline (467.254 us; speedup 1.0000x reference)
//
#include <hip/hip_runtime.h>

// LocalAttention: B=4, N=4096, DIM=1024, H=16, HD=64, WINDOW=256, EXT=128
// R7: 256x256 tile, 8 waves (2Mx4N), wave tile 128x64 kept from R6, but the
// sync schedule restored to counted-vmcnt (T4): per tile, vmcnt(8) -> barrier
// -> front-load ALL 24 frag reads to regs -> lgkm(0) -> barrier -> stage t+2
// into the CURRENT buffer (safe: contents now in regs) -> 64 MFMA (setprio).
// 2 LDS buffers (128KB), loads fly 2 tiles ahead, queue never drains in-loop.
// Epilogue reordered to complete 128B lines consecutively. XCD-chunked block
// swizzle clusters same-A-panel blocks per XCD. Attention unchanged.

typedef __attribute__((ext_vector_type(8))) short short8;
typedef __attribute__((ext_vector_type(4))) float f32x4;
typedef __attribute__((ext_vector_type(8))) unsigned short ushort8v;
typedef __attribute__((ext_vector_type(4))) unsigned short ushort4v;
typedef __attribute__((ext_vector_type(4))) unsigned int uint4v;
typedef __attribute__((ext_vector_type(4))) _Float16 half4;

#define K_DIM 1024

__device__ __forceinline__ unsigned short f2bf(float f) {
  unsigned int u = __builtin_bit_cast(unsigned int, f);
  u += 0x7FFFu + ((u >> 16) & 1u);
  return (unsigned short)(u >> 16);
}
__device__ __forceinline__ unsigned short f2h(float f) {
  _Float16 h = (_Float16)f;
  return __builtin_bit_cast(unsigned short, h);
}
__device__ __forceinline__ void gload_lds(const unsigned short* g, unsigned short* l) {
  __builtin_amdgcn_global_load_lds((const __attribute__((address_space(1))) void*)g,
                                   (__attribute__((address_space(3))) void*)l, 16, 0, 0);
}

// ---------------- fp32 -> bf16 convert ----------------
__global__ __launch_bounds__(256) void convf2b(const float* __restrict__ src,
                                               unsigned short* __restrict__ dst, int n4) {
  int i = blockIdx.x * blockDim.x + threadIdx.x;
  if (i >= n4) return;
  f32x4 v = *(const f32x4*)(src + (size_t)i * 4);
  ushort4v o;
  o[0] = f2bf(v[0]); o[1] = f2bf(v[1]); o[2] = f2bf(v[2]); o[3] = f2bf(v[3]);
  *(ushort4v*)(dst + (size_t)i * 4) = o;
}

// ---------------- 256x256 2-buffer counted-vmcnt GEMM core ----------------
// C(256x256) = A * Bw^T, K=1024, BK=64, 512 threads = 8 waves (2M x 4N),
// wave tile 128x64 (8x4 frags of 16x16x32 bf16 MFMA), acc 128 VGPR.
// LDS: 2 buffers x (A 256x64 + B 256x64) = 2 x 64KB.
// Tile t: vmcnt(8) [t landed; t+1's 8 loads may stay in flight] -> barrier ->
// 24 ds_read_b128 (both ksubs) -> lgkm(0) -> barrier [all waves' reads done]
// -> stage t+2 into buf t&1 [contents in regs] -> 64 MFMA.
// Staged loads issued at t, consumed at t+2: ~2 K-tiles of slack.
// LDS rows 128B = 8 x 16B segs; seg ^= (row&7) swizzle on the GLOBAL source
// (gload_lds dest stays linear), same XOR on ds_read (verified 0 conflicts).
__device__ __forceinline__ void gemm256_core(const unsigned short* __restrict__ A,
                                             const unsigned short* __restrict__ Bw,
                                             unsigned short* lds,
                                             int m0, int f0, int tid, f32x4 acc[8][4]) {
  const int lane = tid & 63;
  const int w = tid >> 6;
  const int wm = w >> 2, wn = w & 3;
  const int q15 = lane & 15, quad = lane >> 4;
  const int r7 = q15 & 7;

  const unsigned short* Ag = A + (size_t)m0 * K_DIM;
  const unsigned short* Bg = Bw + (size_t)f0 * K_DIM;

  // staging geometry: 16B slot = row*8 + s (row 0..255); global seg = s^(row&7)
  int goff[4];
#pragma unroll
  for (int r = 0; r < 4; ++r) {
    int slot = r * 512 + tid;            // 0..2047
    int row = slot >> 3, s = slot & 7;
    goff[r] = row * K_DIM + (s ^ (row & 7)) * 8;   // shorts from panel base
  }

  auto stage = [&](int bb, int kk) {
#pragma unroll
    for (int r = 0; r < 4; ++r)
      gload_lds(Ag + goff[r] + kk, lds + bb * 32768 + (r * 512 + w * 64) * 8);
#pragma unroll
    for (int r = 0; r < 4; ++r)
      gload_lds(Bg + goff[r] + kk, lds + bb * 32768 + 16384 + (r * 512 + w * 64) * 8);
  };

  stage(0, 0);                                    // prologue: tiles 0,1
  stage(1, 64);

  const int abase = (wm * 128 + q15) * 64;        // + i*1024 per 16-row frag
  const int bbase = 16384 + (wn * 64 + q15) * 64; // + j*1024
  const int sg0 = quad ^ r7;
  const int sg1 = (4 | quad) ^ r7;

  auto tile = [&](int t, bool st, bool last) {
    const unsigned short* Lb = lds + (t & 1) * 32768;
    if (last) asm volatile("s_waitcnt vmcnt(0)" ::: "memory");
    else      asm volatile("s_waitcnt vmcnt(8)" ::: "memory");
    __builtin_amdgcn_s_barrier();
    __builtin_amdgcn_sched_barrier(0);
    short8 af0[8], af1[8], bf0[4], bf1[4];
#pragma unroll
    for (int i = 0; i < 8; ++i) {
      af0[i] = *(const short8*)&Lb[abase + i * 1024 + sg0 * 8];
      af1[i] = *(const short8*)&Lb[abase + i * 1024 + sg1 * 8];
    }
#pragma unroll
    for (int j = 0; j < 4; ++j) {
      bf0[j] = *(const short8*)&Lb[bbase + j * 1024 + sg0 * 8];
      bf1[j] = *(const short8*)&Lb[bbase + j * 1024 + sg1 * 8];
    }
    asm volatile("s_waitcnt lgkmcnt(0)" ::: "memory");
    __builtin_amdgcn_sched_barrier(0);
    __builtin_amdgcn_s_barrier();        // all waves finished reading this buf
    if (st) stage(t & 1, (t + 2) * 64);  // overwrite current buf with tile t+2
    __builtin_amdgcn_sched_barrier(0);
    __builtin_amdgcn_s_setprio(1);
#pragma unroll
    for (int i = 0; i < 8; ++i)
#pragma unroll
      for (int j = 0; j < 4; ++j)
        acc[i][j] = __builtin_amdgcn_mfma_f32_16x16x32_bf16(af0[i], bf0[j], acc[i][j], 0, 0, 0);
#pragma unroll
    for (int i = 0; i < 8; ++i)
#pragma unroll
      for (int j = 0; j < 4; ++j)
        acc[i][j] = __builtin_amdgcn_mfma_f32_16x16x32_bf16(af1[i], bf1[j], acc[i][j], 0, 0, 0);
    __builtin_amdgcn_s_setprio(0);
  };

#pragma unroll 2
  for (int t = 0; t < 14; ++t) tile(t, true, false);
  tile(14, false, false);   // tile 15 already staged at t=13
  tile(15, false, true);    // nothing in flight behind it: full drain
}

// ---------------- QKV GEMM + bias + scatter to per-head q/k/v ----------------
__global__ __launch_bounds__(512, 2) void gemm_qkv(const unsigned short* __restrict__ A,
                                                   const unsigned short* __restrict__ Bw,
                                                   const float* __restrict__ bias,
                                                   unsigned short* __restrict__ q,
                                                   unsigned short* __restrict__ k,
                                                   unsigned short* __restrict__ v) {
  __shared__ unsigned short lds[65536];        // 2 x 64KB
  // XCD-chunked swizzle: 96 blocks per XCD = 8 m-tiles x 12 f-tiles, so the
  // 12 blocks sharing an A m-panel stay within one XCD's L2.
  int bid = blockIdx.x;                        // 768 blocks
  int xcd = bid & 7, idx = bid >> 3;
  int mt = xcd * 8 + (idx & 7);
  int ft = idx >> 3;                           // 0..11
  int m0 = mt * 256, f0 = ft * 256;
  int tid = threadIdx.x;
  f32x4 acc[8][4] = {};
  gemm256_core(A, Bw, lds, m0, f0, tid, acc);

  int lane = tid & 63;
  int w = tid >> 6;
  int wm = w >> 2, wn = w & 3;
  int q15 = lane & 15, quad = lane >> 4;
  int which = f0 >> 10;                        // block-uniform
  unsigned short* dst = (which == 0) ? q : ((which == 1) ? k : v);
  int hh = ((f0 + wn * 64) >> 6) & 15;         // wave-uniform head
  float bj[4];
#pragma unroll
  for (int j = 0; j < 4; ++j) bj[j] = bias[f0 + wn * 64 + j * 16 + q15];
#pragma unroll
  for (int i = 0; i < 8; ++i) {
#pragma unroll
    for (int r = 0; r < 4; ++r) {
      int m = m0 + wm * 128 + i * 16 + quad * 4 + r;
      int bb = m >> 12, n = m & 4095;
      size_t rowb = ((size_t)(bb * 16 + hh) * 4096 + n) * 64;
#pragma unroll
      for (int j = 0; j < 4; ++j) {          // j inner: complete 128B line
        int d = j * 16 + q15;
        float val = acc[i][j][r] + bj[j];
        dst[rowb + d] = (which == 2) ? f2h(val) : f2bf(val);
      }
    }
  }
}

// ---------------- proj GEMM + bias -> fp32 out ----------------
__global__ __launch_bounds__(512, 2) void gemm_proj(const unsigned short* __restrict__ A,
                                                    const unsigned short* __restrict__ Bw,
                                                    const float* __restrict__ bias,
                                                    float* __restrict__ out) {
  __shared__ unsigned short lds[65536];        // 2 x 64KB
  int bid = blockIdx.x;                        // 256 blocks
  int xcd = bid & 7, idx = bid >> 3;
  int mt = xcd * 8 + (idx & 7);
  int ft = idx >> 3;                           // 0..3
  int m0 = mt * 256, f0 = ft * 256;
  int tid = threadIdx.x;
  f32x4 acc[8][4] = {};
  gemm256_core(A, Bw, lds, m0, f0, tid, acc);

  int lane = tid & 63;
  int w = tid >> 6;
  int wm = w >> 2, wn = w & 3;
  int q15 = lane & 15, quad = lane >> 4;
  float bj[4];
#pragma unroll
  for (int j = 0; j < 4; ++j) bj[j] = bias[f0 + wn * 64 + j * 16 + q15];
#pragma unroll
  for (int i = 0; i < 8; ++i) {
#pragma unroll
    for (int r = 0; r < 4; ++r) {
      int m = m0 + wm * 128 + i * 16 + quad * 4 + r;
      float* orow = out + (size_t)m * 1024 + f0 + wn * 64;
#pragma unroll
      for (int j = 0; j < 4; ++j)
        orow[j * 16 + q15] = acc[i][j][r] + bj[j];
    }
  }
}

// ---------------- V transpose: (B,H,4096,64) -> (B,H,64,4096) fp16 ----------
__global__ __launch_bounds__(256) void transpose_v(const unsigned short* __restrict__ v,
                                                   unsigned short* __restrict__ vt) {
  __shared__ unsigned short tile[64][72];
  int bid = blockIdx.x;
  int bh = bid >> 6;
  int n0 = (bid & 63) * 64;
  int tid = threadIdx.x;
#pragma unroll
  for (int r = 0; r < 2; ++r) {
    int c = tid + r * 256;
    int row = c >> 3, col8 = (c & 7) * 8;
    uint4v dv = *(const uint4v*)&v[((size_t)bh * 4096 + n0 + row) * 64 + col8];
    *(uint4v*)&tile[row][col8] = dv;
  }
  __syncthreads();
#pragma unroll
  for (int r = 0; r < 2; ++r) {
    int c = tid + r * 256;
    int d = c >> 3, n8 = (c & 7) * 8;
    ushort8v o;
#pragma unroll
    for (int ii = 0; ii < 8; ++ii) o[ii] = tile[n8 + ii][d];
    *(ushort8v*)&vt[((size_t)bh * 64 + d) * 4096 + n0 + n8] = o;
  }
}

// ---------------- windowed attention v3 ----------------
// Block = 4 waves; wave owns 16 queries. 512-key window in 4 chunks of 128.
// Pass A: stage K chunks (LDS, dbuf, swizzled) -> S^T tiles -> scaled fp16 in regs.
// Pass B: stage V^T chunks -> exp -> PV (mfma 16x16x16f16) -> normalize, store.
__global__ __launch_bounds__(256) void attn3(const unsigned short* __restrict__ Q,
                                             const unsigned short* __restrict__ Kb,
                                             const unsigned short* __restrict__ Vt,
                                             unsigned short* __restrict__ Ao) {
  __shared__ unsigned short lds2[2][8192];     // 2 x 16KB

  int bid = blockIdx.x;                        // 64 bh * 64 qblocks
  int qb = bid & 63;
  int bh = bid >> 6;
  int b = bh >> 4, h = bh & 15;
  int tid = threadIdx.x, lane = tid & 63, w = tid >> 6;
  int q0 = qb * 64 + w * 16;
  int g = qb >> 2;
  int kst = g * 256 - 128;
  const size_t base = (size_t)bh * 4096 * 64;
  const int q15 = lane & 15, quad = lane >> 4;

  // Q B-frags: lane holds q=q15, d=quad*8+j (+32s)
  short8 bq[2];
#pragma unroll
  for (int s = 0; s < 2; ++s)
    bq[s] = *(const short8*)&Q[base + (size_t)(q0 + q15) * 64 + s * 32 + quad * 8];

  // ---- Pass A: S^T = K * Q^T, packed scaled fp16 in spk ----
  half4 spk[32];
  float mx = -1e30f;

  auto stageK = [&](int c, int buf) {
    int kb = kst + c * 128;
    kb = min(max(kb, 0), 4096 - 128);
    const unsigned short* Kg = Kb + base + (size_t)kb * 64;
#pragma unroll
    for (int i = 0; i < 4; ++i) {
      int slot = tid + i * 256;
      int row = slot >> 3, s = slot & 7;
      int gs = s ^ (row & 7);
      gload_lds(Kg + (size_t)row * 64 + gs * 8, &lds2[buf][(w * 64 + i * 256) * 8]);
    }
  };

  stageK(0, 0);
#pragma unroll
  for (int c = 0; c < 4; ++c) {
    __syncthreads();
    if (c < 3) stageK(c + 1, (c + 1) & 1);
    const unsigned short* Kc = lds2[c & 1];
    int r7 = q15 & 7;
#pragma unroll
    for (int nt = 0; nt < 8; ++nt) {
      int t = c * 8 + nt;
      int ky = kst + c * 128 + nt * 16;
      bool valid = (ky >= 0) && (ky < 4096);
      if (valid) {
        int sg0 = quad ^ r7;
        const unsigned short* kr = &Kc[(nt * 16 + q15) * 64];
        short8 ak0 = *(const short8*)&kr[sg0 * 8];
        short8 ak1 = *(const short8*)&kr[(sg0 ^ 4) * 8];
        f32x4 sa = {0.f, 0.f, 0.f, 0.f};
        sa = __builtin_amdgcn_mfma_f32_16x16x32_bf16(ak0, bq[0], sa, 0, 0, 0);
        sa = __builtin_amdgcn_mfma_f32_16x16x32_bf16(ak1, bq[1], sa, 0, 0, 0);
        float s0 = sa[0] * 0.125f, s1 = sa[1] * 0.125f;
        float s2 = sa[2] * 0.125f, s3 = sa[3] * 0.125f;
        mx = fmaxf(mx, fmaxf(fmaxf(s0, s1), fmaxf(s2, s3)));
        half4 pk;
        pk[0] = (_Float16)s0; pk[1] = (_Float16)s1;
        pk[2] = (_Float16)s2; pk[3] = (_Float16)s3;
        spk[t] = pk;
      } else {
        spk[t] = (half4){(_Float16)0.f, (_Float16)0.f, (_Float16)0.f, (_Float16)0.f};
      }
    }
  }
  // per-query max: lane's scores all belong to query q0+q15
  mx = fmaxf(mx, __shfl_xor(mx, 16, 64));
  mx = fmaxf(mx, __shfl_xor(mx, 32, 64));

  // ---- Pass B: exp + PV ----
  auto stageV = [&](int c, int buf) {
    int kb = kst + c * 128;
    kb = min(max(kb, 0), 4096 - 128);
    const unsigned short* Vg = Vt + (size_t)bh * 64 * 4096 + kb;
#pragma unroll
    for (int i = 0; i < 4; ++i) {
      int slot = tid + i * 256;
      int d = slot >> 4, s = slot & 15;
      int gs = s ^ (d & 15);
      gload_lds(Vg + (size_t)d * 4096 + gs * 8, &lds2[buf][(w * 64 + i * 256) * 8]);
    }
  };

  float sum = 0.f;
  f32x4 oacc[4];
#pragma unroll
  for (int dt = 0; dt < 4; ++dt) oacc[dt] = (f32x4){0.f, 0.f, 0.f, 0.f};

  stageV(0, 0);
#pragma unroll
  for (int c = 0; c < 4; ++c) {
    __syncthreads();
    if (c < 3) stageV(c + 1, (c + 1) & 1);
    const unsigned short* Vc = lds2[c & 1];
#pragma unroll
    for (int nt = 0; nt < 8; ++nt) {
      int t = c * 8 + nt;
      int ky = kst + c * 128 + nt * 16;
      bool valid = (ky >= 0) && (ky < 4096);
      if (!valid) continue;
      half4 sp = spk[t];
      float p0 = __expf((float)sp[0] - mx);
      float p1 = __expf((float)sp[1] - mx);
      float p2 = __expf((float)sp[2] - mx);
      float p3 = __expf((float)sp[3] - mx);
      sum += (p0 + p1) + (p2 + p3);
      half4 pk;
      pk[0] = (_Float16)p0; pk[1] = (_Float16)p1;
      pk[2] = (_Float16)p2; pk[3] = (_Float16)p3;
      int sgb = 2 * nt + (quad >> 1);
      int eo = (quad & 1) * 4;
#pragma unroll
      for (int dt = 0; dt < 4; ++dt) {
        int d = dt * 16 + q15;
        half4 bv = *(const half4*)&Vc[d * 128 + ((sgb ^ q15) * 8) + eo];
        oacc[dt] = __builtin_amdgcn_mfma_f32_16x16x16f16(pk, bv, oacc[dt], 0, 0, 0);
      }
    }
  }
  sum += __shfl_xor(sum, 16, 64);
  sum += __shfl_xor(sum, 32, 64);
  float linv = 1.0f / sum;

  // normalize + store: O C-layout row=q=quad*4+r, col=d=q15+16dt
  float li[4];
#pragma unroll
  for (int r = 0; r < 4; ++r) li[r] = __shfl(linv, quad * 4 + r, 64);
#pragma unroll
  for (int dt = 0; dt < 4; ++dt) {
#pragma unroll
    for (int r = 0; r < 4; ++r) {
      float o = oacc[dt][r] * li[r];
      Ao[(size_t)(b * 4096 + q0 + quad * 4 + r) * 1024 + h * 64 + dt * 16 + q15] = f2bf(o);
    }
  }
}

// ---------------- host ----------------
extern "C" void kernel_launch(void* const* d_in, const int* in_sizes, int n_in,
                              void* d_out, int out_size, void* d_ws, size_t ws_size,
                              hipStream_t stream) {
  const float* x = (const float*)d_in[0];
  const float* w_qkv = (const float*)d_in[1];
  const float* b_qkv = (const float*)d_in[2];
  const float* w_proj = (const float*)d_in[3];
  const float* b_proj = (const float*)d_in[4];
  float* out = (float*)d_out;

  unsigned short* ws = (unsigned short*)d_ws;
  unsigned short* xb = ws;                       // 16777216 elems (reused as vt later)
  unsigned short* wqkvb = ws + 16777216;         // 3145728
  unsigned short* wprojb = ws + 19922944;        // 1048576
  unsigned short* qb = ws + 20971520;            // 16777216
  unsigned short* kb = ws + 37748736;            // 16777216
  unsigned short* vb = ws + 54525952;            // 16777216 (fp16)
  unsigned short* attnb = ws + 71303168;         // 16777216
  unsigned short* vtb = xb;                      // alias: xb dead after gemm_qkv

  convf2b<<<16384, 256, 0, stream>>>(x, xb, 16777216 / 4);
  convf2b<<<3072, 256, 0, stream>>>(w_qkv, wqkvb, 3145728 / 4);
  convf2b<<<1024, 256, 0, stream>>>(w_proj, wprojb, 1048576 / 4);
  gemm_qkv<<<768, 512, 0, stream>>>(xb, wqkvb, b_qkv, qb, kb, vb);
  transpose_v<<<4096, 256, 0, stream>>>(vb, vtb);
  attn3<<<4096, 256, 0, stream>>>(qb, kb, vtb, attnb);
  gemm_proj<<<256, 512, 0, stream>>>(attnb, wprojb, b_proj, out);
}

// Round 7
// 359.164 us; speedup vs baseline: 1.3009x; 1.3009x over previous
//
#include <hip/hip_runtime.h>

// LocalAttention: B=4, N=4096, DIM=1024, H=16, HD=64, WINDOW=256, EXT=128
// R10 = R8 with the prologue race FIXED: the steady-state schedule stages
// A(t+1) at c0/c1 and B(t+2) at c2/c3, so tile 1's B must be staged by the
// prologue ("tile -1's c2/c3"). R8/R9 never staged B(1) -> tile 1 consumed
// uninitialized LDS -> NaN. Prologue now stages tile0 A+B (8 loads) and
// tile1 B (4 loads), waits vmcnt(4) (keep B(1) in flight, matching steady
// state). Everything else identical to R8: 256x256 tile, 8 waves (2Mx4N),
// wave tile 128x64, BK=64, 2 LDS bufs, 4 phases/K-tile {reads -> stage half
// -> barrier -> lgkm(0) -> 16 MFMA -> barrier}, counted vmcnt(4) once per
// K-tile. Swizzle + XCD block swizzle kept. Attention unchanged.

typedef __attribute__((ext_vector_type(8))) short short8;
typedef __attribute__((ext_vector_type(4))) float f32x4;
typedef __attribute__((ext_vector_type(8))) unsigned short ushort8v;
typedef __attribute__((ext_vector_type(4))) unsigned short ushort4v;
typedef __attribute__((ext_vector_type(4))) unsigned int uint4v;
typedef __attribute__((ext_vector_type(4))) _Float16 half4;

#define K_DIM 1024

__device__ __forceinline__ unsigned short f2bf(float f) {
  unsigned int u = __builtin_bit_cast(unsigned int, f);
  u += 0x7FFFu + ((u >> 16) & 1u);
  return (unsigned short)(u >> 16);
}
__device__ __forceinline__ unsigned short f2h(float f) {
  _Float16 h = (_Float16)f;
  return __builtin_bit_cast(unsigned short, h);
}
__device__ __forceinline__ void gload_lds(const unsigned short* g, unsigned short* l) {
  __builtin_amdgcn_global_load_lds((const __attribute__((address_space(1))) void*)g,
                                   (__attribute__((address_space(3))) void*)l, 16, 0, 0);
}

// ---------------- fp32 -> bf16 convert ----------------
__global__ __launch_bounds__(256) void convf2b(const float* __restrict__ src,
                                               unsigned short* __restrict__ dst, int n4) {
  int i = blockIdx.x * blockDim.x + threadIdx.x;
  if (i >= n4) return;
  f32x4 v = *(const f32x4*)(src + (size_t)i * 4);
  ushort4v o;
  o[0] = f2bf(v[0]); o[1] = f2bf(v[1]); o[2] = f2bf(v[2]); o[3] = f2bf(v[3]);
  *(ushort4v*)(dst + (size_t)i * 4) = o;
}

// ---------------- 256x256 8-phase GEMM core ----------------
// C(256x256) = A * Bw^T, K=1024, 512 threads = 8 waves (2M x 4N), wave tile
// 128x64 (8x4 frags of 16x16x32 bf16), BK=64, 2 LDS bufs x 64KB.
// Phases per K-tile t (buf b = t&1):
//   c0: read A-k0(i0-3)+B-k0 [8]; stage A-h0(t+1)->buf^1; MFMA A(i0-3)xB-k0
//   c1: read A-k0(i4-7)+B-k1 [8]; stage A-h1(t+1)->buf^1; MFMA A(i4-7)xB-k0
//   c2: read A-k1(i0-3) [4];      stage B-h0(t+2)->buf;   MFMA A(i0-3)xB-k1
//   c3: read A-k1(i4-7) [4];      stage B-h1(t+2)->buf;   MFMA A(i4-7)xB-k1
// Each phase: reads+stage issued, then barrier -> lgkm(0) -> setprio(1) ->
// 16 MFMA -> setprio(0) -> [vmcnt(4) at c3 only] -> trailing barrier.
// Trailing barrier follows each wave's lgkm(0) => phase reads have LANDED
// block-wide before the next phase's staging overwrites that region.
// vmcnt ledger (per thread, 4 loads per staged panel-pair... 2 per half):
//   prologue: tile0 A+B (8) + tile1 B (4) -> vmcnt(4) keeps B(1) in flight.
//   steady c3-end: B(t+1).4 | A(t+1).4 | B(t+2).4 = 12 -> vmcnt(4) drains
//   B(t+1)+A(t+1), leaves B(t+2). t=14 ends vmcnt(0); t=15 stages nothing.
// LDS rows 128B = 8x16B segs; seg ^= (row&7) on the GLOBAL source (gload_lds
// dest stays linear), same XOR on ds_read (verified 0 conflicts).
__device__ __forceinline__ void gemm256_core(const unsigned short* __restrict__ A,
                                             const unsigned short* __restrict__ Bw,
                                             unsigned short* lds,
                                             int m0, int f0, int tid, f32x4 acc[8][4]) {
  const int lane = tid & 63;
  const int w = tid >> 6;
  const int wm = w >> 2, wn = w & 3;
  const int q15 = lane & 15, quad = lane >> 4;
  const int r7 = q15 & 7;

  const unsigned short* Ag = A + (size_t)m0 * K_DIM;
  const unsigned short* Bg = Bw + (size_t)f0 * K_DIM;

  // staging geometry: 16B slot = row*8 + s (row 0..255); global seg = s^(row&7)
  int goff[4];
#pragma unroll
  for (int r = 0; r < 4; ++r) {
    int slot = r * 512 + tid;            // 0..2047
    int row = slot >> 3, s = slot & 7;
    goff[r] = row * K_DIM + (s ^ (row & 7)) * 8;   // shorts from panel base
  }

  // hf: 0 = A rows 0-127, 1 = A rows 128-255, 2 = B rows 0-127, 3 = B rows 128-255
  auto stage_half = [&](int bb, int kk, int hf) {
    if (hf < 2) {
#pragma unroll
      for (int r2 = 0; r2 < 2; ++r2) {
        int r = hf * 2 + r2;
        gload_lds(Ag + goff[r] + kk, lds + bb * 32768 + (r * 512 + w * 64) * 8);
      }
    } else {
#pragma unroll
      for (int r2 = 0; r2 < 2; ++r2) {
        int r = (hf - 2) * 2 + r2;
        gload_lds(Bg + goff[r] + kk, lds + bb * 32768 + 16384 + (r * 512 + w * 64) * 8);
      }
    }
  };

  // prologue: tile 0 fully (A+B -> buf0), PLUS tile 1's B (-> buf1, acting as
  // "tile -1's c2/c3"). Drain tile 0's 8, keep B(1)'s 4 in flight.
#pragma unroll
  for (int hf = 0; hf < 4; ++hf) stage_half(0, 0, hf);
  stage_half(1, 64, 2);
  stage_half(1, 64, 3);
  asm volatile("s_waitcnt vmcnt(4)" ::: "memory");
  __builtin_amdgcn_s_barrier();

  const int abase = (wm * 128 + q15) * 64;        // + i*1024 per 16-row frag
  const int bbase = 16384 + (wn * 64 + q15) * 64; // + j*1024
  const int sg0 = quad ^ r7;
  const int sg1 = (4 | quad) ^ r7;

  short8 aq[4], bk0[4], bk1[4];

  for (int t = 0; t < 16; ++t) {
    const int b = t & 1;
    const unsigned short* Lb = lds + b * 32768;

    // ---- phase c0: reads A-k0(i0-3)+B-k0; stage A-h0(t+1); MFMA A(i0-3)xB-k0
#pragma unroll
    for (int i = 0; i < 4; ++i) aq[i] = *(const short8*)&Lb[abase + i * 1024 + sg0 * 8];
#pragma unroll
    for (int j = 0; j < 4; ++j) bk0[j] = *(const short8*)&Lb[bbase + j * 1024 + sg0 * 8];
    if (t <= 14) stage_half(b ^ 1, (t + 1) * 64, 0);
    __builtin_amdgcn_s_barrier();
    asm volatile("s_waitcnt lgkmcnt(0)" ::: "memory");
    __builtin_amdgcn_sched_barrier(0);
    __builtin_amdgcn_s_setprio(1);
#pragma unroll
    for (int i = 0; i < 4; ++i)
#pragma unroll
      for (int j = 0; j < 4; ++j)
        acc[i][j] = __builtin_amdgcn_mfma_f32_16x16x32_bf16(aq[i], bk0[j], acc[i][j], 0, 0, 0);
    __builtin_amdgcn_s_setprio(0);
    __builtin_amdgcn_s_barrier();

    // ---- phase c1: reads A-k0(i4-7)+B-k1; stage A-h1(t+1); MFMA A(i4-7)xB-k0
#pragma unroll
    for (int i = 0; i < 4; ++i) aq[i] = *(const short8*)&Lb[abase + (i + 4) * 1024 + sg0 * 8];
#pragma unroll
    for (int j = 0; j < 4; ++j) bk1[j] = *(const short8*)&Lb[bbase + j * 1024 + sg1 * 8];
    if (t <= 14) stage_half(b ^ 1, (t + 1) * 64, 1);
    __builtin_amdgcn_s_barrier();
    asm volatile("s_waitcnt lgkmcnt(0)" ::: "memory");
    __builtin_amdgcn_sched_barrier(0);
    __builtin_amdgcn_s_setprio(1);
#pragma unroll
    for (int i = 0; i < 4; ++i)
#pragma unroll
      for (int j = 0; j < 4; ++j)
        acc[i + 4][j] = __builtin_amdgcn_mfma_f32_16x16x32_bf16(aq[i], bk0[j], acc[i + 4][j], 0, 0, 0);
    __builtin_amdgcn_s_setprio(0);
    __builtin_amdgcn_s_barrier();

    // ---- phase c2: reads A-k1(i0-3); stage B-h0(t+2) into CURRENT buf (B dead)
#pragma unroll
    for (int i = 0; i < 4; ++i) aq[i] = *(const short8*)&Lb[abase + i * 1024 + sg1 * 8];
    if (t <= 13) stage_half(b, (t + 2) * 64, 2);
    __builtin_amdgcn_s_barrier();
    asm volatile("s_waitcnt lgkmcnt(0)" ::: "memory");
    __builtin_amdgcn_sched_barrier(0);
    __builtin_amdgcn_s_setprio(1);
#pragma unroll
    for (int i = 0; i < 4; ++i)
#pragma unroll
      for (int j = 0; j < 4; ++j)
        acc[i][j] = __builtin_amdgcn_mfma_f32_16x16x32_bf16(aq[i], bk1[j], acc[i][j], 0, 0, 0);
    __builtin_amdgcn_s_setprio(0);
    __builtin_amdgcn_s_barrier();

    // ---- phase c3: reads A-k1(i4-7); stage B-h1(t+2); MFMA; counted vmcnt
#pragma unroll
    for (int i = 0; i < 4; ++i) aq[i] = *(const short8*)&Lb[abase + (i + 4) * 1024 + sg1 * 8];
    if (t <= 13) stage_half(b, (t + 2) * 64, 3);
    __builtin_amdgcn_s_barrier();
    asm volatile("s_waitcnt lgkmcnt(0)" ::: "memory");
    __builtin_amdgcn_sched_barrier(0);
    __builtin_amdgcn_s_setprio(1);
#pragma unroll
    for (int i = 0; i < 4; ++i)
#pragma unroll
      for (int j = 0; j < 4; ++j)
        acc[i + 4][j] = __builtin_amdgcn_mfma_f32_16x16x32_bf16(aq[i], bk1[j], acc[i + 4][j], 0, 0, 0);
    __builtin_amdgcn_s_setprio(0);
    if (t <= 13)      asm volatile("s_waitcnt vmcnt(4)" ::: "memory");
    else if (t == 14) asm volatile("s_waitcnt vmcnt(0)" ::: "memory");
    __builtin_amdgcn_s_barrier();
  }
}

// ---------------- QKV GEMM + bias + scatter to per-head q/k/v ----------------
__global__ __launch_bounds__(512, 2) void gemm_qkv(const unsigned short* __restrict__ A,
                                                   const unsigned short* __restrict__ Bw,
                                                   const float* __restrict__ bias,
                                                   unsigned short* __restrict__ q,
                                                   unsigned short* __restrict__ k,
                                                   unsigned short* __restrict__ v) {
  __shared__ unsigned short lds[65536];        // 2 x 64KB
  // XCD-chunked swizzle: 96 blocks per XCD = 8 m-tiles x 12 f-tiles.
  int bid = blockIdx.x;                        // 768 blocks
  int xcd = bid & 7, idx = bid >> 3;
  int mt = xcd * 8 + (idx & 7);
  int ft = idx >> 3;                           // 0..11
  int m0 = mt * 256, f0 = ft * 256;
  int tid = threadIdx.x;
  f32x4 acc[8][4] = {};
  gemm256_core(A, Bw, lds, m0, f0, tid, acc);

  int lane = tid & 63;
  int w = tid >> 6;
  int wm = w >> 2, wn = w & 3;
  int q15 = lane & 15, quad = lane >> 4;
  int which = f0 >> 10;                        // block-uniform
  unsigned short* dst = (which == 0) ? q : ((which == 1) ? k : v);
  int hh = ((f0 + wn * 64) >> 6) & 15;         // wave-uniform head
  float bj[4];
#pragma unroll
  for (int j = 0; j < 4; ++j) bj[j] = bias[f0 + wn * 64 + j * 16 + q15];
#pragma unroll
  for (int i = 0; i < 8; ++i) {
#pragma unroll
    for (int r = 0; r < 4; ++r) {
      int m = m0 + wm * 128 + i * 16 + quad * 4 + r;
      int bb = m >> 12, n = m & 4095;
      size_t rowb = ((size_t)(bb * 16 + hh) * 4096 + n) * 64;
#pragma unroll
      for (int j = 0; j < 4; ++j) {          // j inner: complete 128B line
        int d = j * 16 + q15;
        float val = acc[i][j][r] + bj[j];
        dst[rowb + d] = (which == 2) ? f2h(val) : f2bf(val);
      }
    }
  }
}

// ---------------- proj GEMM + bias -> fp32 out ----------------
__global__ __launch_bounds__(512, 2) void gemm_proj(const unsigned short* __restrict__ A,
                                                    const unsigned short* __restrict__ Bw,
                                                    const float* __restrict__ bias,
                                                    float* __restrict__ out) {
  __shared__ unsigned short lds[65536];        // 2 x 64KB
  int bid = blockIdx.x;                        // 256 blocks
  int xcd = bid & 7, idx = bid >> 3;
  int mt = xcd * 8 + (idx & 7);
  int ft = idx >> 3;                           // 0..3
  int m0 = mt * 256, f0 = ft * 256;
  int tid = threadIdx.x;
  f32x4 acc[8][4] = {};
  gemm256_core(A, Bw, lds, m0, f0, tid, acc);

  int lane = tid & 63;
  int w = tid >> 6;
  int wm = w >> 2, wn = w & 3;
  int q15 = lane & 15, quad = lane >> 4;
  float bj[4];
#pragma unroll
  for (int j = 0; j < 4; ++j) bj[j] = bias[f0 + wn * 64 + j * 16 + q15];
#pragma unroll
  for (int i = 0; i < 8; ++i) {
#pragma unroll
    for (int r = 0; r < 4; ++r) {
      int m = m0 + wm * 128 + i * 16 + quad * 4 + r;
      float* orow = out + (size_t)m * 1024 + f0 + wn * 64;
#pragma unroll
      for (int j = 0; j < 4; ++j)
        orow[j * 16 + q15] = acc[i][j][r] + bj[j];
    }
  }
}

// ---------------- V transpose: (B,H,4096,64) -> (B,H,64,4096) fp16 ----------
__global__ __launch_bounds__(256) void transpose_v(const unsigned short* __restrict__ v,
                                                   unsigned short* __restrict__ vt) {
  __shared__ unsigned short tile[64][72];
  int bid = blockIdx.x;
  int bh = bid >> 6;
  int n0 = (bid & 63) * 64;
  int tid = threadIdx.x;
#pragma unroll
  for (int r = 0; r < 2; ++r) {
    int c = tid + r * 256;
    int row = c >> 3, col8 = (c & 7) * 8;
    uint4v dv = *(const uint4v*)&v[((size_t)bh * 4096 + n0 + row) * 64 + col8];
    *(uint4v*)&tile[row][col8] = dv;
  }
  __syncthreads();
#pragma unroll
  for (int r = 0; r < 2; ++r) {
    int c = tid + r * 256;
    int d = c >> 3, n8 = (c & 7) * 8;
    ushort8v o;
#pragma unroll
    for (int ii = 0; ii < 8; ++ii) o[ii] = tile[n8 + ii][d];
    *(ushort8v*)&vt[((size_t)bh * 64 + d) * 4096 + n0 + n8] = o;
  }
}

// ---------------- windowed attention v3 ----------------
__global__ __launch_bounds__(256) void attn3(const unsigned short* __restrict__ Q,
                                             const unsigned short* __restrict__ Kb,
                                             const unsigned short* __restrict__ Vt,
                                             unsigned short* __restrict__ Ao) {
  __shared__ unsigned short lds2[2][8192];     // 2 x 16KB

  int bid = blockIdx.x;                        // 64 bh * 64 qblocks
  int qb = bid & 63;
  int bh = bid >> 6;
  int b = bh >> 4, h = bh & 15;
  int tid = threadIdx.x, lane = tid & 63, w = tid >> 6;
  int q0 = qb * 64 + w * 16;
  int g = qb >> 2;
  int kst = g * 256 - 128;
  const size_t base = (size_t)bh * 4096 * 64;
  const int q15 = lane & 15, quad = lane >> 4;

  short8 bq[2];
#pragma unroll
  for (int s = 0; s < 2; ++s)
    bq[s] = *(const short8*)&Q[base + (size_t)(q0 + q15) * 64 + s * 32 + quad * 8];

  half4 spk[32];
  float mx = -1e30f;

  auto stageK = [&](int c, int buf) {
    int kb = kst + c * 128;
    kb = min(max(kb, 0), 4096 - 128);
    const unsigned short* Kg = Kb + base + (size_t)kb * 64;
#pragma unroll
    for (int i = 0; i < 4; ++i) {
      int slot = tid + i * 256;
      int row = slot >> 3, s = slot & 7;
      int gs = s ^ (row & 7);
      gload_lds(Kg + (size_t)row * 64 + gs * 8, &lds2[buf][(w * 64 + i * 256) * 8]);
    }
  };

  stageK(0, 0);
#pragma unroll
  for (int c = 0; c < 4; ++c) {
    __syncthreads();
    if (c < 3) stageK(c + 1, (c + 1) & 1);
    const unsigned short* Kc = lds2[c & 1];
    int r7 = q15 & 7;
#pragma unroll
    for (int nt = 0; nt < 8; ++nt) {
      int t = c * 8 + nt;
      int ky = kst + c * 128 + nt * 16;
      bool valid = (ky >= 0) && (ky < 4096);
      if (valid) {
        int sg0 = quad ^ r7;
        const unsigned short* kr = &Kc[(nt * 16 + q15) * 64];
        short8 ak0 = *(const short8*)&kr[sg0 * 8];
        short8 ak1 = *(const short8*)&kr[(sg0 ^ 4) * 8];
        f32x4 sa = {0.f, 0.f, 0.f, 0.f};
        sa = __builtin_amdgcn_mfma_f32_16x16x32_bf16(ak0, bq[0], sa, 0, 0, 0);
        sa = __builtin_amdgcn_mfma_f32_16x16x32_bf16(ak1, bq[1], sa, 0, 0, 0);
        float s0 = sa[0] * 0.125f, s1 = sa[1] * 0.125f;
        float s2 = sa[2] * 0.125f, s3 = sa[3] * 0.125f;
        mx = fmaxf(mx, fmaxf(fmaxf(s0, s1), fmaxf(s2, s3)));
        half4 pk;
        pk[0] = (_Float16)s0; pk[1] = (_Float16)s1;
        pk[2] = (_Float16)s2; pk[3] = (_Float16)s3;
        spk[t] = pk;
      } else {
        spk[t] = (half4){(_Float16)0.f, (_Float16)0.f, (_Float16)0.f, (_Float16)0.f};
      }
    }
  }
  mx = fmaxf(mx, __shfl_xor(mx, 16, 64));
  mx = fmaxf(mx, __shfl_xor(mx, 32, 64));

  auto stageV = [&](int c, int buf) {
    int kb = kst + c * 128;
    kb = min(max(kb, 0), 4096 - 128);
    const unsigned short* Vg = Vt + (size_t)bh * 64 * 4096 + kb;
#pragma unroll
    for (int i = 0; i < 4; ++i) {
      int slot = tid + i * 256;
      int d = slot >> 4, s = slot & 15;
      int gs = s ^ (d & 15);
      gload_lds(Vg + (size_t)d * 4096 + gs * 8, &lds2[buf][(w * 64 + i * 256) * 8]);
    }
  };

  float sum = 0.f;
  f32x4 oacc[4];
#pragma unroll
  for (int dt = 0; dt < 4; ++dt) oacc[dt] = (f32x4){0.f, 0.f, 0.f, 0.f};

  stageV(0, 0);
#pragma unroll
  for (int c = 0; c < 4; ++c) {
    __syncthreads();
    if (c < 3) stageV(c + 1, (c + 1) & 1);
    const unsigned short* Vc = lds2[c & 1];
#pragma unroll
    for (int nt = 0; nt < 8; ++nt) {
      int t = c * 8 + nt;
      int ky = kst + c * 128 + nt * 16;
      bool valid = (ky >= 0) && (ky < 4096);
      if (!valid) continue;
      half4 sp = spk[t];
      float p0 = __expf((float)sp[0] - mx);
      float p1 = __expf((float)sp[1] - mx);
      float p2 = __expf((float)sp[2] - mx);
      float p3 = __expf((float)sp[3] - mx);
      sum += (p0 + p1) + (p2 + p3);
      half4 pk;
      pk[0] = (_Float16)p0; pk[1] = (_Float16)p1;
      pk[2] = (_Float16)p2; pk[3] = (_Float16)p3;
      int sgb = 2 * nt + (quad >> 1);
      int eo = (quad & 1) * 4;
#pragma unroll
      for (int dt = 0; dt < 4; ++dt) {
        int d = dt * 16 + q15;
        half4 bv = *(const half4*)&Vc[d * 128 + ((sgb ^ q15) * 8) + eo];
        oacc[dt] = __builtin_amdgcn_mfma_f32_16x16x16f16(pk, bv, oacc[dt], 0, 0, 0);
      }
    }
  }
  sum += __shfl_xor(sum, 16, 64);
  sum += __shfl_xor(sum, 32, 64);
  float linv = 1.0f / sum;

  float li[4];
#pragma unroll
  for (int r = 0; r < 4; ++r) li[r] = __shfl(linv, quad * 4 + r, 64);
#pragma unroll
  for (int dt = 0; dt < 4; ++dt) {
#pragma unroll
    for (int r = 0; r < 4; ++r) {
      float o = oacc[dt][r] * li[r];
      Ao[(size_t)(b * 4096 + q0 + quad * 4 + r) * 1024 + h * 64 + dt * 16 + q15] = f2bf(o);
    }
  }
}

// ---------------- host ----------------
extern "C" void kernel_launch(void* const* d_in, const int* in_sizes, int n_in,
                              void* d_out, int out_size, void* d_ws, size_t ws_size,
                              hipStream_t stream) {
  const float* x = (const float*)d_in[0];
  const float* w_qkv = (const float*)d_in[1];
  const float* b_qkv = (const float*)d_in[2];
  const float* w_proj = (const float*)d_in[3];
  const float* b_proj = (const float*)d_in[4];
  float* out = (float*)d_out;

  unsigned short* ws = (unsigned short*)d_ws;
  unsigned short* xb = ws;                       // 16777216 elems (reused as vt later)
  unsigned short* wqkvb = ws + 16777216;         // 3145728
  unsigned short* wprojb = ws + 19922944;        // 1048576
  unsigned short* qb = ws + 20971520;            // 16777216
  unsigned short* kb = ws + 37748736;            // 16777216
  unsigned short* vb = ws + 54525952;            // 16777216 (fp16)
  unsigned short* attnb = ws + 71303168;         // 16777216
  unsigned short* vtb = xb;                      // alias: xb dead after gemm_qkv

  convf2b<<<16384, 256, 0, stream>>>(x, xb, 16777216 / 4);
  convf2b<<<3072, 256, 0, stream>>>(w_qkv, wqkvb, 3145728 / 4);
  convf2b<<<1024, 256, 0, stream>>>(w_proj, wprojb, 1048576 / 4);
  gemm_qkv<<<768, 512, 0, stream>>>(xb, wqkvb, b_qkv, qb, kb, vb);
  transpose_v<<<4096, 256, 0, stream>>>(vb, vtb);
  attn3<<<4096, 256, 0, stream>>>(qb, kb, vtb, attnb);
  gemm_proj<<<256, 512, 0, stream>>>(attnb, wprojb, b_proj, out);
}